// Round 4
// baseline (433.105 us; speedup 1.0000x reference)
//
#include <hip/hip_runtime.h>
#include <hip/hip_fp16.h>
#include <stdint.h>

typedef unsigned short u16;
typedef unsigned int u32;
typedef short bf16x8 __attribute__((ext_vector_type(8)));
typedef _Float16 half8 __attribute__((ext_vector_type(8)));
typedef float f32x4 __attribute__((ext_vector_type(4)));

__device__ __forceinline__ float bf2f(u16 v) { return __uint_as_float(((u32)v) << 16); }

__device__ __forceinline__ u16 f2bf(float a) {
  u32 u = __float_as_uint(a); u += 0x7FFFu + ((u >> 16) & 1u); return (u16)(u >> 16);
}

// pack two floats to two bf16 (RNE) in one dword
__device__ __forceinline__ u32 packbf2(float a, float b) {
  u32 ua = __float_as_uint(a); ua += 0x7FFFu + ((ua >> 16) & 1u);
  u32 ub = __float_as_uint(b); ub += 0x7FFFu + ((ub >> 16) & 1u);
  return (ua >> 16) | (ub & 0xFFFF0000u);
}

// pack two floats to two fp16 (RNE via v_cvt_f16_f32) in one dword
__device__ __forceinline__ u32 packh2(float a, float b) {
  return (u32)__half_as_ushort(__float2half(a)) |
         ((u32)__half_as_ushort(__float2half(b)) << 16);
}

// read element idx from a vector that is fp32 (isf=1) or bf16 (isf=0)
__device__ __forceinline__ float inval(const void* p, int idx, int isf) {
  return isf ? ((const float*)p)[idx] : bf2f(((const u16*)p)[idx]);
}

// ---------------------------------------------------------------------------
// Detect input dtype: flag=1 means inputs are fp32 (evidence: r1-3 say yes).
// ---------------------------------------------------------------------------
__global__ void detect_kernel(const u16* __restrict__ w1raw, int* __restrict__ flag)
{
  int lane = threadIdx.x & 63;
  float m = 0.f;
  #pragma unroll
  for (int j = 0; j < 2; ++j) {
    float v = fabsf(bf2f(w1raw[lane + j * 64]));
    if (!(v < 1e6f)) v = 1e30f;
    m = fmaxf(m, v);
  }
  #pragma unroll
  for (int off = 32; off; off >>= 1) m = fmaxf(m, __shfl_xor(m, off));
  if (lane == 0) *flag = (m > 1e6f) ? 1 : 0;
}

// ---------------------------------------------------------------------------
// Split ingest: row length 256 -> 768 bf16 cols. lo_pos=1: [hi|lo|hi] (A-side);
// lo_pos=2: [hi|hi|lo] (B-side). Gives exact fp32 product via 3 MFMA blocks.
// ---------------------------------------------------------------------------
__global__ __launch_bounds__(256) void split_kernel(
    const void* __restrict__ src, u16* __restrict__ dst,
    const int* __restrict__ flag, int n4, int lo_pos)
{
  int i = blockIdx.x * 256 + threadIdx.x;   // one group of 4 elements
  if (i >= n4) return;
  int row = i >> 6, g = i & 63;             // 64 groups per 256-col row
  float v[4];
  if (*flag) {
    float4 t = ((const float4*)src)[i];
    v[0] = t.x; v[1] = t.y; v[2] = t.z; v[3] = t.w;
  } else {
    uint2 t = ((const uint2*)src)[i];
    const u16* p = (const u16*)&t;
    v[0] = bf2f(p[0]); v[1] = bf2f(p[1]); v[2] = bf2f(p[2]); v[3] = bf2f(p[3]);
  }
  u16 hi[4]; float lo[4];
  #pragma unroll
  for (int j = 0; j < 4; ++j) { hi[j] = f2bf(v[j]); lo[j] = v[j] - bf2f(hi[j]); }
  u32 hw0 = (u32)hi[0] | ((u32)hi[1] << 16);
  u32 hw1 = (u32)hi[2] | ((u32)hi[3] << 16);
  u32 lw0 = packbf2(lo[0], lo[1]);
  u32 lw1 = packbf2(lo[2], lo[3]);
  u32* base = (u32*)(dst + (size_t)row * 768);
  int c = g * 2;                            // u32 index in 128-u32 block
  base[c] = hw0; base[c + 1] = hw1;
  if (lo_pos == 1) {
    base[128 + c] = lw0; base[128 + c + 1] = lw1;
    base[256 + c] = hw0; base[256 + c + 1] = hw1;
  } else {
    base[128 + c] = hw0; base[128 + c + 1] = hw1;
    base[256 + c] = lw0; base[256 + c + 1] = lw1;
  }
}

// ---------------------------------------------------------------------------
// Kernel 1: h = x @ W1^T + b1 via split-bf16 (K=768, exact to ~2^-18),
// fp32 out + per-block sum/sumsq. Tile 128n x 64o, grid (32,8).
// ---------------------------------------------------------------------------
#define L1_LD 136
__global__ __launch_bounds__(256) void l1_kernel(
    const u16* __restrict__ xs, const u16* __restrict__ w1s, const void* __restrict__ b1,
    const int* __restrict__ flag, float* __restrict__ H, float2* __restrict__ PT)
{
  __shared__ u16 sA[128 * L1_LD];
  __shared__ u16 sB[64 * L1_LD];
  __shared__ float redbuf[8];
  const int n0 = blockIdx.x * 128, o0 = blockIdx.y * 64;
  const int t = threadIdx.x, wave = t >> 6, lane = t & 63, quad = lane >> 4, l16 = lane & 15;
  const int isf = *flag;
  f32x4 acc[2][4] = {};
  for (int ks = 0; ks < 768; ks += 128) {
    #pragma unroll
    for (int r = 0; r < 8; ++r) {
      int idx = t + r * 256;
      int row = idx >> 4, col = idx & 15;
      const uint4* src = (const uint4*)(xs + (size_t)(n0 + row) * 768 + ks) + col;
      *(uint4*)&sA[row * L1_LD + col * 8] = *src;
    }
    #pragma unroll
    for (int r = 0; r < 4; ++r) {
      int idx = t + r * 256;
      int row = idx >> 4, col = idx & 15;
      const uint4* src = (const uint4*)(w1s + (size_t)(o0 + row) * 768 + ks) + col;
      *(uint4*)&sB[row * L1_LD + col * 8] = *src;
    }
    __syncthreads();
    #pragma unroll
    for (int kk = 0; kk < 128; kk += 32) {
      bf16x8 bfr[4];
      #pragma unroll
      for (int fo = 0; fo < 4; ++fo)
        bfr[fo] = *(const bf16x8*)&sB[(fo * 16 + l16) * L1_LD + kk + quad * 8];
      #pragma unroll
      for (int fm = 0; fm < 2; ++fm) {
        bf16x8 av = *(const bf16x8*)&sA[(wave * 32 + fm * 16 + l16) * L1_LD + kk + quad * 8];
        #pragma unroll
        for (int fo = 0; fo < 4; ++fo)
          acc[fm][fo] = __builtin_amdgcn_mfma_f32_16x16x32_bf16(av, bfr[fo], acc[fm][fo], 0, 0, 0);
      }
    }
    __syncthreads();
  }
  float s = 0.f, sq = 0.f;
  #pragma unroll
  for (int fm = 0; fm < 2; ++fm)
  #pragma unroll
  for (int fo = 0; fo < 4; ++fo) {
    int o = o0 + fo * 16 + l16;
    float bias = inval(b1, o, isf);
    #pragma unroll
    for (int r = 0; r < 4; ++r) {
      int n = n0 + wave * 32 + fm * 16 + quad * 4 + r;
      float h = acc[fm][fo][r] + bias;
      H[(size_t)n * 512 + o] = h;
      s += h; sq += h * h;
    }
  }
  #pragma unroll
  for (int off = 32; off; off >>= 1) { s += __shfl_down(s, off); sq += __shfl_down(sq, off); }
  if (lane == 0) { redbuf[wave] = s; redbuf[4 + wave] = sq; }
  __syncthreads();
  if (t == 0) {
    float S = redbuf[0] + redbuf[1] + redbuf[2] + redbuf[3];
    float Q = redbuf[4] + redbuf[5] + redbuf[6] + redbuf[7];
    PT[blockIdx.y * 32 + blockIdx.x] = make_float2(S, Q);
  }
}

// ---------------------------------------------------------------------------
// Kernel 2: reduce 256 partials -> mean, rsqrt(var+eps)
// ---------------------------------------------------------------------------
__global__ __launch_bounds__(256) void red_kernel(const float2* __restrict__ PT, float* __restrict__ ST)
{
  __shared__ float sa[4], sb[4];
  const int t = threadIdx.x;
  float2 p = PT[t];
  float s = p.x, q = p.y;
  #pragma unroll
  for (int off = 32; off; off >>= 1) { s += __shfl_down(s, off); q += __shfl_down(q, off); }
  if ((t & 63) == 0) { sa[t >> 6] = s; sb[t >> 6] = q; }
  __syncthreads();
  if (t == 0) {
    float S = sa[0] + sa[1] + sa[2] + sa[3];
    float Q = sb[0] + sb[1] + sb[2] + sb[3];
    const float N = 4096.f * 512.f;
    float mean = S / N;
    float var = Q / N - mean * mean;
    ST[0] = mean;
    ST[1] = rsqrtf(var + 1e-5f);
  }
}

// ---------------------------------------------------------------------------
// Prep: reorder coeffs to K-interleaved fp16 rows.
// W2F[o][i*32 + t]: t<16 -> c2[0,o,i,t] (cos), t>=16 -> c2[1,o,i,t-16] (sin)
// ---------------------------------------------------------------------------
__global__ __launch_bounds__(256) void prep2_kernel(
    const void* __restrict__ c2, u16* __restrict__ w2f, const int* __restrict__ flag)
{
  int u = blockIdx.x * 256 + threadIdx.x;  // 512*512
  int o = u >> 9, i = u & 511;
  u32* d = (u32*)(w2f + (size_t)o * 16384 + i * 32);
  if (*flag) {
    const float4* f0 = (const float4*)((const float*)c2 + ((size_t)o * 512 + i) * 16);
    const float4* f1 = (const float4*)((const float*)c2 + (size_t)512 * 512 * 16 + ((size_t)o * 512 + i) * 16);
    #pragma unroll
    for (int j = 0; j < 4; ++j) { float4 v = f0[j]; d[2*j] = packh2(v.x, v.y); d[2*j+1] = packh2(v.z, v.w); }
    #pragma unroll
    for (int j = 0; j < 4; ++j) { float4 v = f1[j]; d[8+2*j] = packh2(v.x, v.y); d[8+2*j+1] = packh2(v.z, v.w); }
  } else {
    const u16* s0 = (const u16*)c2 + ((size_t)o * 512 + i) * 16;
    const u16* s1 = (const u16*)c2 + (size_t)512 * 512 * 16 + ((size_t)o * 512 + i) * 16;
    #pragma unroll
    for (int j = 0; j < 8; ++j) d[j]   = packh2(bf2f(s0[2*j]), bf2f(s0[2*j+1]));
    #pragma unroll
    for (int j = 0; j < 8; ++j) d[8+j] = packh2(bf2f(s1[2*j]), bf2f(s1[2*j+1]));
  }
}

__global__ __launch_bounds__(256) void prep3_kernel(
    const void* __restrict__ c3, u16* __restrict__ w3f, const int* __restrict__ flag)
{
  int u = blockIdx.x * 256 + threadIdx.x;  // 256*512
  int o = u >> 9, i = u & 511;
  u32* d = (u32*)(w3f + (size_t)o * 8192 + i * 16);
  if (*flag) {
    const float4* f0 = (const float4*)((const float*)c3 + ((size_t)o * 512 + i) * 8);
    const float4* f1 = (const float4*)((const float*)c3 + (size_t)256 * 512 * 8 + ((size_t)o * 512 + i) * 8);
    #pragma unroll
    for (int j = 0; j < 2; ++j) { float4 v = f0[j]; d[2*j] = packh2(v.x, v.y); d[2*j+1] = packh2(v.z, v.w); }
    #pragma unroll
    for (int j = 0; j < 2; ++j) { float4 v = f1[j]; d[4+2*j] = packh2(v.x, v.y); d[4+2*j+1] = packh2(v.z, v.w); }
  } else {
    const u16* s0 = (const u16*)c3 + ((size_t)o * 512 + i) * 8;
    const u16* s1 = (const u16*)c3 + (size_t)256 * 512 * 8 + ((size_t)o * 512 + i) * 8;
    #pragma unroll
    for (int j = 0; j < 4; ++j) d[j]   = packh2(bf2f(s0[2*j]), bf2f(s0[2*j+1]));
    #pragma unroll
    for (int j = 0; j < 4; ++j) d[4+j] = packh2(bf2f(s1[2*j]), bf2f(s1[2*j+1]));
  }
}

// ---------------------------------------------------------------------------
// Kernel 3: fused BN+ReLU + Fourier basis (grid=16) + fp16 GEMM -> H2 (f32)
// Block tile 128n x 64o, K = 512 i * 32 slots = 16384, KT = 128 (4 i/step).
// ---------------------------------------------------------------------------
#define K2_LD 136
__global__ __launch_bounds__(256) void kan2_kernel(
    const float* __restrict__ H, const u16* __restrict__ w2f, const void* __restrict__ bias2,
    const void* __restrict__ gammap, const void* __restrict__ betap,
    const int* __restrict__ flag, const float* __restrict__ ST, float* __restrict__ H2)
{
  __shared__ u16 sA[128 * K2_LD];
  __shared__ u16 sB[64 * K2_LD];
  const int n0 = blockIdx.x * 128, o0 = blockIdx.y * 64;
  const int t = threadIdx.x, wave = t >> 6, lane = t & 63, quad = lane >> 4, l16 = lane & 15;
  const int isf = *flag;
  const float mean = ST[0];
  const float gs = inval(gammap, 0, isf) * ST[1];
  const float beta = inval(betap, 0, isf);
  const int bo = t >> 2, bseg = t & 3;
  f32x4 acc[2][4] = {};
  for (int ib = 0; ib < 512; ib += 4) {
    {
      const uint4* src = (const uint4*)(w2f + (size_t)(o0 + bo) * 16384 + (size_t)ib * 32 + bseg * 32);
      uint4* dst = (uint4*)&sB[bo * K2_LD + bseg * 32];
      dst[0] = src[0]; dst[1] = src[1]; dst[2] = src[2]; dst[3] = src[3];
    }
    #pragma unroll
    for (int p = 0; p < 2; ++p) {
      int pair = t + p * 256;
      int m = pair >> 2, ii = pair & 3;
      float h = H[(size_t)(n0 + m) * 512 + ib + ii];
      float a = fmaxf((h - mean) * gs + beta, 0.f);
      float s1, c1; __sincosf(a, &s1, &c1);
      float cg[16], sg[16];
      cg[0] = c1; sg[0] = s1;
      #pragma unroll
      for (int g = 1; g < 16; ++g) {
        cg[g] = cg[g-1] * c1 - sg[g-1] * s1;
        sg[g] = sg[g-1] * c1 + cg[g-1] * s1;
      }
      u32* dst = (u32*)&sA[m * K2_LD + ii * 32];
      #pragma unroll
      for (int j = 0; j < 8; ++j) dst[j] = packh2(cg[2*j], cg[2*j+1]);
      #pragma unroll
      for (int j = 0; j < 8; ++j) dst[8+j] = packh2(sg[2*j], sg[2*j+1]);
    }
    __syncthreads();
    #pragma unroll
    for (int kk = 0; kk < 128; kk += 32) {
      half8 bfr[4];
      #pragma unroll
      for (int fo = 0; fo < 4; ++fo)
        bfr[fo] = *(const half8*)&sB[(fo * 16 + l16) * K2_LD + kk + quad * 8];
      #pragma unroll
      for (int fm = 0; fm < 2; ++fm) {
        half8 av = *(const half8*)&sA[(wave * 32 + fm * 16 + l16) * K2_LD + kk + quad * 8];
        #pragma unroll
        for (int fo = 0; fo < 4; ++fo)
          acc[fm][fo] = __builtin_amdgcn_mfma_f32_16x16x32_f16(av, bfr[fo], acc[fm][fo], 0, 0, 0);
      }
    }
    __syncthreads();
  }
  #pragma unroll
  for (int fm = 0; fm < 2; ++fm)
  #pragma unroll
  for (int fo = 0; fo < 4; ++fo) {
    int o = o0 + fo * 16 + l16;
    float b2 = inval(bias2, o, isf);
    #pragma unroll
    for (int r = 0; r < 4; ++r) {
      int n = n0 + wave * 32 + fm * 16 + quad * 4 + r;
      H2[(size_t)n * 512 + o] = acc[fm][fo][r] + b2;
    }
  }
}

// ---------------------------------------------------------------------------
// Kernel 4: Fourier basis (grid=8) + fp16 GEMM -> logits (4096x256 f32)
// Block tile 64n x 64o, K = 512 i * 16 slots = 8192, KT = 128 (8 i/step).
// ---------------------------------------------------------------------------
#define K3_LD 136
__global__ __launch_bounds__(256) void kan3_kernel(
    const float* __restrict__ H2, const u16* __restrict__ w3f, const void* __restrict__ bias3,
    const int* __restrict__ flag, float* __restrict__ LG)
{
  __shared__ u16 sA[64 * K3_LD];
  __shared__ u16 sB[64 * K3_LD];
  const int n0 = blockIdx.x * 64, o0 = blockIdx.y * 64;
  const int t = threadIdx.x, wave = t >> 6, lane = t & 63, quad = lane >> 4, l16 = lane & 15;
  const int isf = *flag;
  const int bo = t >> 2, bseg = t & 3;
  f32x4 acc[4] = {};
  for (int ib = 0; ib < 512; ib += 8) {
    {
      const uint4* src = (const uint4*)(w3f + (size_t)(o0 + bo) * 8192 + (size_t)ib * 16 + bseg * 32);
      uint4* dst = (uint4*)&sB[bo * K3_LD + bseg * 32];
      dst[0] = src[0]; dst[1] = src[1]; dst[2] = src[2]; dst[3] = src[3];
    }
    #pragma unroll
    for (int p = 0; p < 2; ++p) {
      int pair = t + p * 256;
      int m = pair >> 3, ii = pair & 7;
      float a = H2[(size_t)(n0 + m) * 512 + ib + ii];
      float s1, c1; __sincosf(a, &s1, &c1);
      float cg[8], sg[8];
      cg[0] = c1; sg[0] = s1;
      #pragma unroll
      for (int g = 1; g < 8; ++g) {
        cg[g] = cg[g-1] * c1 - sg[g-1] * s1;
        sg[g] = sg[g-1] * c1 + cg[g-1] * s1;
      }
      u32* dst = (u32*)&sA[m * K3_LD + ii * 16];
      #pragma unroll
      for (int j = 0; j < 4; ++j) dst[j] = packh2(cg[2*j], cg[2*j+1]);
      #pragma unroll
      for (int j = 0; j < 4; ++j) dst[4+j] = packh2(sg[2*j], sg[2*j+1]);
    }
    __syncthreads();
    #pragma unroll
    for (int kk = 0; kk < 128; kk += 32) {
      half8 bfr[4];
      #pragma unroll
      for (int fo = 0; fo < 4; ++fo)
        bfr[fo] = *(const half8*)&sB[(fo * 16 + l16) * K3_LD + kk + quad * 8];
      half8 av = *(const half8*)&sA[(wave * 16 + l16) * K3_LD + kk + quad * 8];
      #pragma unroll
      for (int fo = 0; fo < 4; ++fo)
        acc[fo] = __builtin_amdgcn_mfma_f32_16x16x32_f16(av, bfr[fo], acc[fo], 0, 0, 0);
    }
    __syncthreads();
  }
  #pragma unroll
  for (int fo = 0; fo < 4; ++fo) {
    int o = o0 + fo * 16 + l16;
    float b3 = inval(bias3, o, isf);
    #pragma unroll
    for (int r = 0; r < 4; ++r) {
      int n = n0 + wave * 16 + quad * 4 + r;
      LG[(size_t)n * 256 + o] = acc[fo][r] + b3;
    }
  }
}

// ---------------------------------------------------------------------------
// Kernel 5: row softmax (256 cols) + fp32 store. One wave per row.
// ---------------------------------------------------------------------------
__global__ __launch_bounds__(256) void softmax_kernel(const float* __restrict__ LG, float* __restrict__ out)
{
  const int t = threadIdx.x, wave = t >> 6, lane = t & 63;
  const int row = blockIdx.x * 4 + wave;
  float4 v = *(const float4*)(LG + (size_t)row * 256 + lane * 4);
  float m = fmaxf(fmaxf(v.x, v.y), fmaxf(v.z, v.w));
  #pragma unroll
  for (int off = 32; off; off >>= 1) m = fmaxf(m, __shfl_xor(m, off));
  float e0 = __expf(v.x - m), e1 = __expf(v.y - m), e2 = __expf(v.z - m), e3 = __expf(v.w - m);
  float s = e0 + e1 + e2 + e3;
  #pragma unroll
  for (int off = 32; off; off >>= 1) s += __shfl_xor(s, off);
  float inv = 1.f / s;
  float4 o = make_float4(e0 * inv, e1 * inv, e2 * inv, e3 * inv);
  *(float4*)(out + (size_t)row * 256 + lane * 4) = o;
}

// ---------------------------------------------------------------------------
extern "C" void kernel_launch(void* const* d_in, const int* in_sizes, int n_in,
                              void* d_out, int out_size, void* d_ws, size_t ws_size,
                              hipStream_t stream)
{
  const void* x     = d_in[0];
  const void* W1    = d_in[1];
  const void* b1    = d_in[2];
  const void* gamma = d_in[3];
  const void* beta  = d_in[4];
  const void* c2    = d_in[5];
  const void* bias2 = d_in[6];
  const void* c3    = d_in[7];
  const void* bias3 = d_in[8];

  char* ws = (char*)d_ws;
  float*  H    = (float*)(ws + 0);                        // 8 MB (4096x512 f32), alias LG
  float*  H2   = (float*)(ws + (8ull  << 20));            // 8 MB (4096x512 f32)
  u16*    Xs   = (u16*)  (ws + (8ull  << 20));            // 6.3 MB (4096x768 bf16), dead before kan2 writes H2
  u16*    W1s  = (u16*)  (ws + (8ull  << 20) + 6815744);  // 0.79 MB (512x768 bf16), inside H2 window too
  u16*    W2F  = (u16*)  (ws + (16ull << 20));            // 16 MB (512x16384 fp16)
  u16*    W3F  = (u16*)  (ws + (32ull << 20));            // 4 MB (256x8192 fp16)
  float2* PT   = (float2*)(ws + (36ull << 20) + 524288);  // 2 KB
  float*  STT  = (float*) (ws + (36ull << 20) + 589824);  // 8 B
  int*    FLAG = (int*)   (ws + (36ull << 20) + 655360);  // 4 B
  float*  LG   = (float*)(ws + 0);                        // alias H (dead after kan2)

  detect_kernel<<<dim3(1), dim3(64), 0, stream>>>((const u16*)W1, FLAG);
  split_kernel<<<dim3(1024), dim3(256), 0, stream>>>(x,  Xs,  FLAG, 262144, 1);  // A: [hi|lo|hi]
  split_kernel<<<dim3(128),  dim3(256), 0, stream>>>(W1, W1s, FLAG, 32768,  2);  // B: [hi|hi|lo]
  prep2_kernel<<<dim3(1024), dim3(256), 0, stream>>>(c2, W2F, FLAG);
  prep3_kernel<<<dim3(512),  dim3(256), 0, stream>>>(c3, W3F, FLAG);
  l1_kernel   <<<dim3(32, 8), dim3(256), 0, stream>>>(Xs, W1s, b1, FLAG, H, PT);
  red_kernel  <<<dim3(1),    dim3(256), 0, stream>>>(PT, STT);
  kan2_kernel <<<dim3(32, 8), dim3(256), 0, stream>>>(H, W2F, bias2, gamma, beta, FLAG, STT, H2);
  kan3_kernel <<<dim3(64, 4), dim3(256), 0, stream>>>(H2, W3F, bias3, FLAG, LG);
  softmax_kernel<<<dim3(1024), dim3(256), 0, stream>>>(LG, (float*)d_out);
}

// Round 5
// 304.887 us; speedup vs baseline: 1.4205x; 1.4205x over previous
//
#include <hip/hip_runtime.h>
#include <hip/hip_fp16.h>
#include <stdint.h>

typedef unsigned short u16;
typedef unsigned int u32;
typedef short bf16x8 __attribute__((ext_vector_type(8)));
typedef _Float16 half8 __attribute__((ext_vector_type(8)));
typedef float f32x4 __attribute__((ext_vector_type(4)));

__device__ __forceinline__ float bf2f(u16 v) { return __uint_as_float(((u32)v) << 16); }

__device__ __forceinline__ u16 f2bf(float a) {
  u32 u = __float_as_uint(a); u += 0x7FFFu + ((u >> 16) & 1u); return (u16)(u >> 16);
}

__device__ __forceinline__ u32 packbf2(float a, float b) {
  u32 ua = __float_as_uint(a); ua += 0x7FFFu + ((ua >> 16) & 1u);
  u32 ub = __float_as_uint(b); ub += 0x7FFFu + ((ub >> 16) & 1u);
  return (ua >> 16) | (ub & 0xFFFF0000u);
}

__device__ __forceinline__ u32 packh2(float a, float b) {
  return (u32)__half_as_ushort(__float2half(a)) |
         ((u32)__half_as_ushort(__float2half(b)) << 16);
}

__device__ __forceinline__ float inval(const void* p, int idx, int isf) {
  return isf ? ((const float*)p)[idx] : bf2f(((const u16*)p)[idx]);
}

// ---------------------------------------------------------------------------
// Detect input dtype: flag=1 -> fp32 inputs (verified r3/r4 on this dataset).
// ---------------------------------------------------------------------------
__global__ void detect_kernel(const u16* __restrict__ w1raw, int* __restrict__ flag)
{
  int lane = threadIdx.x & 63;
  float m = 0.f;
  #pragma unroll
  for (int j = 0; j < 2; ++j) {
    float v = fabsf(bf2f(w1raw[lane + j * 64]));
    if (!(v < 1e6f)) v = 1e30f;
    m = fmaxf(m, v);
  }
  #pragma unroll
  for (int off = 32; off; off >>= 1) m = fmaxf(m, __shfl_xor(m, off));
  if (lane == 0) *flag = (m > 1e6f) ? 1 : 0;
}

// ---------------------------------------------------------------------------
// Split ingest: row 256 -> 768 bf16 cols. lo_pos=1: [hi|lo|hi]; 2: [hi|hi|lo].
// 3-block split-bf16 gives exact fp32 product (residual ~2^-18).
// ---------------------------------------------------------------------------
__global__ __launch_bounds__(256) void split_kernel(
    const void* __restrict__ src, u16* __restrict__ dst,
    const int* __restrict__ flag, int n4, int lo_pos)
{
  int i = blockIdx.x * 256 + threadIdx.x;
  if (i >= n4) return;
  int row = i >> 6, g = i & 63;
  float v[4];
  if (*flag) {
    float4 t = ((const float4*)src)[i];
    v[0] = t.x; v[1] = t.y; v[2] = t.z; v[3] = t.w;
  } else {
    uint2 t = ((const uint2*)src)[i];
    const u16* p = (const u16*)&t;
    v[0] = bf2f(p[0]); v[1] = bf2f(p[1]); v[2] = bf2f(p[2]); v[3] = bf2f(p[3]);
  }
  u16 hi[4]; float lo[4];
  #pragma unroll
  for (int j = 0; j < 4; ++j) { hi[j] = f2bf(v[j]); lo[j] = v[j] - bf2f(hi[j]); }
  u32 hw0 = (u32)hi[0] | ((u32)hi[1] << 16);
  u32 hw1 = (u32)hi[2] | ((u32)hi[3] << 16);
  u32 lw0 = packbf2(lo[0], lo[1]);
  u32 lw1 = packbf2(lo[2], lo[3]);
  u32* base = (u32*)(dst + (size_t)row * 768);
  int c = g * 2;
  base[c] = hw0; base[c + 1] = hw1;
  if (lo_pos == 1) {
    base[128 + c] = lw0; base[128 + c + 1] = lw1;
    base[256 + c] = hw0; base[256 + c + 1] = hw1;
  } else {
    base[128 + c] = hw0; base[128 + c + 1] = hw1;
    base[256 + c] = lw0; base[256 + c + 1] = lw1;
  }
}

// ---------------------------------------------------------------------------
// Kernel 1: h = x @ W1^T + b1 via split-bf16 (K=768), fp32 out + sum/sumsq.
// Tile 128n x 64o, grid (32,8).
// ---------------------------------------------------------------------------
#define L1_LD 136
__global__ __launch_bounds__(256) void l1_kernel(
    const u16* __restrict__ xs, const u16* __restrict__ w1s, const void* __restrict__ b1,
    const int* __restrict__ flag, float* __restrict__ H, float2* __restrict__ PT)
{
  __shared__ u16 sA[128 * L1_LD];
  __shared__ u16 sB[64 * L1_LD];
  __shared__ float redbuf[8];
  const int n0 = blockIdx.x * 128, o0 = blockIdx.y * 64;
  const int t = threadIdx.x, wave = t >> 6, lane = t & 63, quad = lane >> 4, l16 = lane & 15;
  const int isf = *flag;
  f32x4 acc[2][4] = {};
  for (int ks = 0; ks < 768; ks += 128) {
    #pragma unroll
    for (int r = 0; r < 8; ++r) {
      int idx = t + r * 256;
      int row = idx >> 4, col = idx & 15;
      const uint4* src = (const uint4*)(xs + (size_t)(n0 + row) * 768 + ks) + col;
      *(uint4*)&sA[row * L1_LD + col * 8] = *src;
    }
    #pragma unroll
    for (int r = 0; r < 4; ++r) {
      int idx = t + r * 256;
      int row = idx >> 4, col = idx & 15;
      const uint4* src = (const uint4*)(w1s + (size_t)(o0 + row) * 768 + ks) + col;
      *(uint4*)&sB[row * L1_LD + col * 8] = *src;
    }
    __syncthreads();
    #pragma unroll
    for (int kk = 0; kk < 128; kk += 32) {
      bf16x8 bfr[4];
      #pragma unroll
      for (int fo = 0; fo < 4; ++fo)
        bfr[fo] = *(const bf16x8*)&sB[(fo * 16 + l16) * L1_LD + kk + quad * 8];
      #pragma unroll
      for (int fm = 0; fm < 2; ++fm) {
        bf16x8 av = *(const bf16x8*)&sA[(wave * 32 + fm * 16 + l16) * L1_LD + kk + quad * 8];
        #pragma unroll
        for (int fo = 0; fo < 4; ++fo)
          acc[fm][fo] = __builtin_amdgcn_mfma_f32_16x16x32_bf16(av, bfr[fo], acc[fm][fo], 0, 0, 0);
      }
    }
    __syncthreads();
  }
  float s = 0.f, sq = 0.f;
  #pragma unroll
  for (int fm = 0; fm < 2; ++fm)
  #pragma unroll
  for (int fo = 0; fo < 4; ++fo) {
    int o = o0 + fo * 16 + l16;
    float bias = inval(b1, o, isf);
    #pragma unroll
    for (int r = 0; r < 4; ++r) {
      int n = n0 + wave * 32 + fm * 16 + quad * 4 + r;
      float h = acc[fm][fo][r] + bias;
      H[(size_t)n * 512 + o] = h;
      s += h; sq += h * h;
    }
  }
  #pragma unroll
  for (int off = 32; off; off >>= 1) { s += __shfl_down(s, off); sq += __shfl_down(sq, off); }
  if (lane == 0) { redbuf[wave] = s; redbuf[4 + wave] = sq; }
  __syncthreads();
  if (t == 0) {
    float S = redbuf[0] + redbuf[1] + redbuf[2] + redbuf[3];
    float Q = redbuf[4] + redbuf[5] + redbuf[6] + redbuf[7];
    PT[blockIdx.y * 32 + blockIdx.x] = make_float2(S, Q);
  }
}

// ---------------------------------------------------------------------------
// Kernel 2: reduce 256 partials -> mean, rsqrt(var+eps)
// ---------------------------------------------------------------------------
__global__ __launch_bounds__(256) void red_kernel(const float2* __restrict__ PT, float* __restrict__ ST)
{
  __shared__ float sa[4], sb[4];
  const int t = threadIdx.x;
  float2 p = PT[t];
  float s = p.x, q = p.y;
  #pragma unroll
  for (int off = 32; off; off >>= 1) { s += __shfl_down(s, off); q += __shfl_down(q, off); }
  if ((t & 63) == 0) { sa[t >> 6] = s; sb[t >> 6] = q; }
  __syncthreads();
  if (t == 0) {
    float S = sa[0] + sa[1] + sa[2] + sa[3];
    float Q = sb[0] + sb[1] + sb[2] + sb[3];
    const float N = 4096.f * 512.f;
    float mean = S / N;
    float var = Q / N - mean * mean;
    ST[0] = mean;
    ST[1] = rsqrtf(var + 1e-5f);
  }
}

// ---------------------------------------------------------------------------
// Prep: reorder coeffs to K-interleaved fp16 rows.
// ---------------------------------------------------------------------------
__global__ __launch_bounds__(256) void prep2_kernel(
    const void* __restrict__ c2, u16* __restrict__ w2f, const int* __restrict__ flag)
{
  int u = blockIdx.x * 256 + threadIdx.x;  // 512*512
  int o = u >> 9, i = u & 511;
  u32* d = (u32*)(w2f + (size_t)o * 16384 + i * 32);
  if (*flag) {
    const float4* f0 = (const float4*)((const float*)c2 + ((size_t)o * 512 + i) * 16);
    const float4* f1 = (const float4*)((const float*)c2 + (size_t)512 * 512 * 16 + ((size_t)o * 512 + i) * 16);
    #pragma unroll
    for (int j = 0; j < 4; ++j) { float4 v = f0[j]; d[2*j] = packh2(v.x, v.y); d[2*j+1] = packh2(v.z, v.w); }
    #pragma unroll
    for (int j = 0; j < 4; ++j) { float4 v = f1[j]; d[8+2*j] = packh2(v.x, v.y); d[8+2*j+1] = packh2(v.z, v.w); }
  } else {
    const u16* s0 = (const u16*)c2 + ((size_t)o * 512 + i) * 16;
    const u16* s1 = (const u16*)c2 + (size_t)512 * 512 * 16 + ((size_t)o * 512 + i) * 16;
    #pragma unroll
    for (int j = 0; j < 8; ++j) d[j]   = packh2(bf2f(s0[2*j]), bf2f(s0[2*j+1]));
    #pragma unroll
    for (int j = 0; j < 8; ++j) d[8+j] = packh2(bf2f(s1[2*j]), bf2f(s1[2*j+1]));
  }
}

__global__ __launch_bounds__(256) void prep3_kernel(
    const void* __restrict__ c3, u16* __restrict__ w3f, const int* __restrict__ flag)
{
  int u = blockIdx.x * 256 + threadIdx.x;  // 256*512
  int o = u >> 9, i = u & 511;
  u32* d = (u32*)(w3f + (size_t)o * 8192 + i * 16);
  if (*flag) {
    const float4* f0 = (const float4*)((const float*)c3 + ((size_t)o * 512 + i) * 8);
    const float4* f1 = (const float4*)((const float*)c3 + (size_t)256 * 512 * 8 + ((size_t)o * 512 + i) * 8);
    #pragma unroll
    for (int j = 0; j < 2; ++j) { float4 v = f0[j]; d[2*j] = packh2(v.x, v.y); d[2*j+1] = packh2(v.z, v.w); }
    #pragma unroll
    for (int j = 0; j < 2; ++j) { float4 v = f1[j]; d[4+2*j] = packh2(v.x, v.y); d[4+2*j+1] = packh2(v.z, v.w); }
  } else {
    const u16* s0 = (const u16*)c3 + ((size_t)o * 512 + i) * 8;
    const u16* s1 = (const u16*)c3 + (size_t)256 * 512 * 8 + ((size_t)o * 512 + i) * 8;
    #pragma unroll
    for (int j = 0; j < 4; ++j) d[j]   = packh2(bf2f(s0[2*j]), bf2f(s0[2*j+1]));
    #pragma unroll
    for (int j = 0; j < 4; ++j) d[4+j] = packh2(bf2f(s1[2*j]), bf2f(s1[2*j+1]));
  }
}

// ---------------------------------------------------------------------------
// Kernel 3 v2: fused BN+ReLU+basis + fp16 GEMM, split-K partials.
// Tile 64n x 128o, i-range 256 per kz. Grid (64,4,2) = 512 blocks -> 2/CU.
// Trig dup x4 (o-tiles), was x8. LDS 52224 B.
// ---------------------------------------------------------------------------
#define K2_LD 136
__global__ __launch_bounds__(256) void kan2_kernel(
    const float* __restrict__ H, const u16* __restrict__ w2f,
    const void* __restrict__ gammap, const void* __restrict__ betap,
    const int* __restrict__ flag, const float* __restrict__ ST, float* __restrict__ P)
{
  __shared__ u16 sA[64 * K2_LD];
  __shared__ u16 sB[128 * K2_LD];
  const int n0 = blockIdx.x * 64, o0 = blockIdx.y * 128, kz = blockIdx.z;
  const int t = threadIdx.x, wave = t >> 6, lane = t & 63, quad = lane >> 4, l16 = lane & 15;
  const int wm = (wave & 1) * 32, wo = (wave >> 1) * 64;
  const int isf = *flag;
  const float mean = ST[0];
  const float gs = inval(gammap, 0, isf) * ST[1];
  const float beta = inval(betap, 0, isf);
  const int am = t >> 2, ai = t & 3;
  const int i0 = kz * 256;
  f32x4 acc[2][4] = {};
  for (int ib = 0; ib < 256; ib += 4) {
    // B stage: 128 rows x 128 shorts = 2048 uint4, 8/thread
    #pragma unroll
    for (int r = 0; r < 8; ++r) {
      int idx = t + r * 256;
      int row = idx >> 4, col = idx & 15;
      const uint4* src = (const uint4*)(w2f + (size_t)(o0 + row) * 16384 + (size_t)(i0 + ib) * 32) + col;
      *(uint4*)&sB[row * K2_LD + col * 8] = *src;
    }
    // A stage: 64 rows x 4 i, exactly 1 (m,i) pair per thread
    {
      float h = H[(size_t)(n0 + am) * 512 + i0 + ib + ai];
      float a = fmaxf((h - mean) * gs + beta, 0.f);
      float s1, c1; __sincosf(a, &s1, &c1);
      float cg[16], sg[16];
      cg[0] = c1; sg[0] = s1;
      #pragma unroll
      for (int g = 1; g < 16; ++g) {
        cg[g] = cg[g-1] * c1 - sg[g-1] * s1;
        sg[g] = sg[g-1] * c1 + cg[g-1] * s1;
      }
      u32* dst = (u32*)&sA[am * K2_LD + ai * 32];
      #pragma unroll
      for (int j = 0; j < 8; ++j) dst[j] = packh2(cg[2*j], cg[2*j+1]);
      #pragma unroll
      for (int j = 0; j < 8; ++j) dst[8+j] = packh2(sg[2*j], sg[2*j+1]);
    }
    __syncthreads();
    #pragma unroll
    for (int kk = 0; kk < 128; kk += 32) {
      half8 bfr[4], afr[2];
      #pragma unroll
      for (int fo = 0; fo < 4; ++fo)
        bfr[fo] = *(const half8*)&sB[(wo + fo * 16 + l16) * K2_LD + kk + quad * 8];
      #pragma unroll
      for (int fm = 0; fm < 2; ++fm)
        afr[fm] = *(const half8*)&sA[(wm + fm * 16 + l16) * K2_LD + kk + quad * 8];
      #pragma unroll
      for (int fm = 0; fm < 2; ++fm)
      #pragma unroll
      for (int fo = 0; fo < 4; ++fo)
        acc[fm][fo] = __builtin_amdgcn_mfma_f32_16x16x32_f16(afr[fm], bfr[fo], acc[fm][fo], 0, 0, 0);
    }
    __syncthreads();
  }
  float* Pk = P + (size_t)kz * (4096 * 512);
  #pragma unroll
  for (int fm = 0; fm < 2; ++fm)
  #pragma unroll
  for (int fo = 0; fo < 4; ++fo) {
    int o = o0 + wo + fo * 16 + l16;
    #pragma unroll
    for (int r = 0; r < 4; ++r) {
      int n = n0 + wm + fm * 16 + quad * 4 + r;
      Pk[(size_t)n * 512 + o] = acc[fm][fo][r];
    }
  }
}

// ---------------------------------------------------------------------------
// Reduce kan2 partials + bias2 -> H2
// ---------------------------------------------------------------------------
__global__ __launch_bounds__(256) void reduce2_kernel(
    const float* __restrict__ P, const void* __restrict__ bias2,
    const int* __restrict__ flag, float* __restrict__ H2)
{
  int i = blockIdx.x * 256 + threadIdx.x;  // 524288 float4 groups
  const int isf = *flag;
  float4 a = ((const float4*)P)[i];
  float4 b = ((const float4*)(P + (size_t)4096 * 512))[i];
  int o = (i * 4) & 511;
  float4 r;
  r.x = a.x + b.x + inval(bias2, o + 0, isf);
  r.y = a.y + b.y + inval(bias2, o + 1, isf);
  r.z = a.z + b.z + inval(bias2, o + 2, isf);
  r.w = a.w + b.w + inval(bias2, o + 3, isf);
  ((float4*)H2)[i] = r;
}

// ---------------------------------------------------------------------------
// Kernel 4 v2: basis (grid=8) + fp16 GEMM, split-K partials.
// Tile 32n x 128o, i-range 256 per kz. Grid (128,2,2) = 512 blocks -> 2/CU.
// LDS 43520 B.
// ---------------------------------------------------------------------------
#define K3_LD 136
__global__ __launch_bounds__(256) void kan3_kernel(
    const float* __restrict__ H2, const u16* __restrict__ w3f,
    const int* __restrict__ flag, float* __restrict__ Q)
{
  __shared__ u16 sA[32 * K3_LD];
  __shared__ u16 sB[128 * K3_LD];
  const int n0 = blockIdx.x * 32, o0 = blockIdx.y * 128, kz = blockIdx.z;
  const int t = threadIdx.x, wave = t >> 6, lane = t & 63, quad = lane >> 4, l16 = lane & 15;
  const int wo = wave * 32;
  const int am = t >> 3, ai = t & 7;
  const int i0 = kz * 256;
  f32x4 acc[2][2] = {};
  for (int ib = 0; ib < 256; ib += 8) {
    // B stage: 128 rows x 128 shorts = 2048 uint4, 8/thread
    #pragma unroll
    for (int r = 0; r < 8; ++r) {
      int idx = t + r * 256;
      int row = idx >> 4, col = idx & 15;
      const uint4* src = (const uint4*)(w3f + (size_t)(o0 + row) * 8192 + (size_t)(i0 + ib) * 16) + col;
      *(uint4*)&sB[row * K3_LD + col * 8] = *src;
    }
    // A stage: 32 rows x 8 i, 1 pair/thread
    {
      float a = H2[(size_t)(n0 + am) * 512 + i0 + ib + ai];
      float s1, c1; __sincosf(a, &s1, &c1);
      float cg[8], sg[8];
      cg[0] = c1; sg[0] = s1;
      #pragma unroll
      for (int g = 1; g < 8; ++g) {
        cg[g] = cg[g-1] * c1 - sg[g-1] * s1;
        sg[g] = sg[g-1] * c1 + cg[g-1] * s1;
      }
      u32* dst = (u32*)&sA[am * K3_LD + ai * 16];
      #pragma unroll
      for (int j = 0; j < 4; ++j) dst[j] = packh2(cg[2*j], cg[2*j+1]);
      #pragma unroll
      for (int j = 0; j < 4; ++j) dst[4+j] = packh2(sg[2*j], sg[2*j+1]);
    }
    __syncthreads();
    #pragma unroll
    for (int kk = 0; kk < 128; kk += 32) {
      half8 bfr[2], afr[2];
      #pragma unroll
      for (int fo = 0; fo < 2; ++fo)
        bfr[fo] = *(const half8*)&sB[(wo + fo * 16 + l16) * K3_LD + kk + quad * 8];
      #pragma unroll
      for (int fm = 0; fm < 2; ++fm)
        afr[fm] = *(const half8*)&sA[(fm * 16 + l16) * K3_LD + kk + quad * 8];
      #pragma unroll
      for (int fm = 0; fm < 2; ++fm)
      #pragma unroll
      for (int fo = 0; fo < 2; ++fo)
        acc[fm][fo] = __builtin_amdgcn_mfma_f32_16x16x32_f16(afr[fm], bfr[fo], acc[fm][fo], 0, 0, 0);
    }
    __syncthreads();
  }
  float* Qk = Q + (size_t)kz * (4096 * 256);
  #pragma unroll
  for (int fm = 0; fm < 2; ++fm)
  #pragma unroll
  for (int fo = 0; fo < 2; ++fo) {
    int o = o0 + wo + fo * 16 + l16;
    #pragma unroll
    for (int r = 0; r < 4; ++r) {
      int n = n0 + fm * 16 + quad * 4 + r;
      Qk[(size_t)n * 256 + o] = acc[fm][fo][r];
    }
  }
}

// ---------------------------------------------------------------------------
// Kernel 5: fused partial-reduce + bias3 + row softmax + fp32 store.
// One wave per row (256 cols).
// ---------------------------------------------------------------------------
__global__ __launch_bounds__(256) void softmax_kernel(
    const float* __restrict__ Q, const void* __restrict__ bias3,
    const int* __restrict__ flag, float* __restrict__ out)
{
  const int t = threadIdx.x, wave = t >> 6, lane = t & 63;
  const int row = blockIdx.x * 4 + wave;
  const int isf = *flag;
  size_t base = (size_t)row * 256 + lane * 4;
  float4 a = *(const float4*)(Q + base);
  float4 b = *(const float4*)(Q + (size_t)4096 * 256 + base);
  int o = lane * 4;
  float v0 = a.x + b.x + inval(bias3, o + 0, isf);
  float v1 = a.y + b.y + inval(bias3, o + 1, isf);
  float v2 = a.z + b.z + inval(bias3, o + 2, isf);
  float v3 = a.w + b.w + inval(bias3, o + 3, isf);
  float m = fmaxf(fmaxf(v0, v1), fmaxf(v2, v3));
  #pragma unroll
  for (int off = 32; off; off >>= 1) m = fmaxf(m, __shfl_xor(m, off));
  float e0 = __expf(v0 - m), e1 = __expf(v1 - m), e2 = __expf(v2 - m), e3 = __expf(v3 - m);
  float s = e0 + e1 + e2 + e3;
  #pragma unroll
  for (int off = 32; off; off >>= 1) s += __shfl_xor(s, off);
  float inv = 1.f / s;
  *(float4*)(out + base) = make_float4(e0 * inv, e1 * inv, e2 * inv, e3 * inv);
}

// ---------------------------------------------------------------------------
extern "C" void kernel_launch(void* const* d_in, const int* in_sizes, int n_in,
                              void* d_out, int out_size, void* d_ws, size_t ws_size,
                              hipStream_t stream)
{
  const void* x     = d_in[0];
  const void* W1    = d_in[1];
  const void* b1    = d_in[2];
  const void* gamma = d_in[3];
  const void* beta  = d_in[4];
  const void* c2    = d_in[5];
  const void* bias2 = d_in[6];
  const void* c3    = d_in[7];
  const void* bias3 = d_in[8];

  char* ws = (char*)d_ws;
  float*  H    = (float*)(ws + 0);                        // 8 MB [l1 -> kan2]
  float*  H2   = (float*)(ws + (8ull  << 20));            // 8 MB [reduce2 -> kan3]
  u16*    W2F  = (u16*)  (ws + (16ull << 20));            // 16 MB [prep2 -> kan2]
  u16*    W3F  = (u16*)  (ws + (32ull << 20));            // 4 MB  [prep3 -> kan3]
  u16*    Xs   = (u16*)  (ws + (36ull << 20));            // 6.3 MB [split -> l1], dead after
  u16*    W1s  = (u16*)  (ws + (43ull << 20));            // 0.79 MB [split -> l1], dead after
  float*  P2   = (float*)(ws + (36ull << 20));            // 16 MB [kan2 -> reduce2], aliases Xs/W1s
  float*  Q3   = (float*)(ws + 0);                        // 8 MB [kan3 -> softmax], aliases H
  float2* PT   = (float2*)(ws + (52ull << 20));           // 2 KB
  float*  STT  = (float*) (ws + (52ull << 20) + 65536);   // 8 B
  int*    FLAG = (int*)   (ws + (52ull << 20) + 131072);  // 4 B

  detect_kernel<<<dim3(1), dim3(64), 0, stream>>>((const u16*)W1, FLAG);
  split_kernel<<<dim3(1024), dim3(256), 0, stream>>>(x,  Xs,  FLAG, 262144, 1);
  split_kernel<<<dim3(128),  dim3(256), 0, stream>>>(W1, W1s, FLAG, 32768,  2);
  prep2_kernel<<<dim3(1024), dim3(256), 0, stream>>>(c2, W2F, FLAG);
  prep3_kernel<<<dim3(512),  dim3(256), 0, stream>>>(c3, W3F, FLAG);
  l1_kernel   <<<dim3(32, 8), dim3(256), 0, stream>>>(Xs, W1s, b1, FLAG, H, PT);
  red_kernel  <<<dim3(1),    dim3(256), 0, stream>>>(PT, STT);
  kan2_kernel <<<dim3(64, 4, 2), dim3(256), 0, stream>>>(H, W2F, gamma, beta, FLAG, STT, P2);
  reduce2_kernel<<<dim3(2048), dim3(256), 0, stream>>>(P2, bias2, FLAG, H2);
  kan3_kernel <<<dim3(128, 2, 2), dim3(256), 0, stream>>>(H2, W3F, FLAG, Q3);
  softmax_kernel<<<dim3(1024), dim3(256), 0, stream>>>(Q3, bias3, FLAG, (float*)d_out);
}